// Round 1
// baseline (72.334 us; speedup 1.0000x reference)
//
#include <hip/hip_runtime.h>
#include <math.h>

#define NQ 4
#define NL 6
#define DIM 16
#define BLOCK 256

// One thread = one batch sample. State (16 complex amps) lives in registers.
// Rot matrices are batch-uniform: threads 0..23 of each block build them in
// LDS once (broadcast reads thereafter -> no bank conflicts).
__global__ __launch_bounds__(BLOCK) void vqc_kernel(
    const float* __restrict__ inputs,   // [B, 4]
    const float* __restrict__ rot,      // [6, 4, 3]
    float* __restrict__ out,            // [B, 4]
    int batch)
{
    __shared__ float U[NL * NQ][8];  // u00r,u00i,u01r,u01i,u10r,u10i,u11r,u11i

    const int tid = threadIdx.x;
    if (tid < NL * NQ) {
        float phi = rot[tid * 3 + 0];
        float theta = rot[tid * 3 + 1];
        float omega = rot[tid * 3 + 2];
        float st, ct;
        __sincosf(0.5f * theta, &st, &ct);
        float a = 0.5f * (phi + omega);   // ep = exp(-i a) = ca - i sa
        float b = 0.5f * (phi - omega);   // em = exp(+i b) = cb + i sb
        float sa, ca, sb, cb;
        __sincosf(a, &sa, &ca);
        __sincosf(b, &sb, &cb);
        U[tid][0] = ca * ct;   // u00 = ep*ct
        U[tid][1] = -sa * ct;
        U[tid][2] = -cb * st;  // u01 = -em*st
        U[tid][3] = -sb * st;
        U[tid][4] = cb * st;   // u10 = conj(em)*st
        U[tid][5] = -sb * st;
        U[tid][6] = ca * ct;   // u11 = conj(ep)*ct
        U[tid][7] = sa * ct;
    }
    __syncthreads();

    const int b = blockIdx.x * BLOCK + tid;
    if (b >= batch) return;

    // ---- AngleEmbedding: product state directly ----
    const float4 x = ((const float4*)inputs)[b];
    float c[NQ], s[NQ];
    __sincosf(0.5f * x.x, &s[0], &c[0]);
    __sincosf(0.5f * x.y, &s[1], &c[1]);
    __sincosf(0.5f * x.z, &s[2], &c[2]);
    __sincosf(0.5f * x.w, &s[3], &c[3]);

    float sr[DIM], si[DIM];
#pragma unroll
    for (int i = 0; i < DIM; ++i) {
        // qubit q <-> bit (3-q) of i
        float mag = (((i >> 3) & 1) ? s[0] : c[0])
                  * (((i >> 2) & 1) ? s[1] : c[1])
                  * (((i >> 1) & 1) ? s[2] : c[2])
                  * (((i >> 0) & 1) ? s[3] : c[3]);
        const int k = (((i >> 3) & 1) + ((i >> 2) & 1) + ((i >> 1) & 1) + (i & 1)) & 3;
        // (-i)^k: 0->(1,0) 1->(0,-1) 2->(-1,0) 3->(0,1)
        sr[i] = (k == 0) ? mag : ((k == 2) ? -mag : 0.0f);
        si[i] = (k == 1) ? -mag : ((k == 3) ? mag : 0.0f);
    }

    // ---- StronglyEntanglingLayers ----
#pragma unroll
    for (int l = 0; l < NL; ++l) {
#pragma unroll
        for (int q = 0; q < NQ; ++q) {
            const float* u = U[l * NQ + q];
            const float u00r = u[0], u00i = u[1], u01r = u[2], u01i = u[3];
            const float u10r = u[4], u10i = u[5], u11r = u[6], u11i = u[7];
            const int m = 1 << (3 - q);
#pragma unroll
            for (int i = 0; i < DIM; ++i) {
                if (!(i & m)) {
                    const int j = i | m;
                    const float a0r = sr[i], a0i = si[i];
                    const float a1r = sr[j], a1i = si[j];
                    sr[i] = u00r * a0r - u00i * a0i + u01r * a1r - u01i * a1i;
                    si[i] = u00r * a0i + u00i * a0r + u01r * a1i + u01i * a1r;
                    sr[j] = u10r * a0r - u10i * a0i + u11r * a1r - u11i * a1i;
                    si[j] = u10r * a0i + u10i * a0r + u11r * a1i + u11i * a1r;
                }
            }
        }
        const int r = l % (NQ - 1) + 1;
#pragma unroll
        for (int q = 0; q < NQ; ++q) {
            const int t = (q + r) & 3;
            const int cm = 1 << (3 - q);
            const int tm = 1 << (3 - t);
#pragma unroll
            for (int i = 0; i < DIM; ++i) {
                if ((i & cm) && !(i & tm)) {
                    const int j = i | tm;
                    float tr = sr[i]; sr[i] = sr[j]; sr[j] = tr;
                    float ti = si[i]; si[i] = si[j]; si[j] = ti;
                }
            }
        }
    }

    // ---- <Z_q> from probabilities ----
    float e0 = 0.f, e1 = 0.f, e2 = 0.f, e3 = 0.f;
#pragma unroll
    for (int i = 0; i < DIM; ++i) {
        const float p = sr[i] * sr[i] + si[i] * si[i];
        e0 += ((i >> 3) & 1) ? -p : p;
        e1 += ((i >> 2) & 1) ? -p : p;
        e2 += ((i >> 1) & 1) ? -p : p;
        e3 += ((i >> 0) & 1) ? -p : p;
    }
    ((float4*)out)[b] = make_float4(e0, e1, e2, e3);
}

extern "C" void kernel_launch(void* const* d_in, const int* in_sizes, int n_in,
                              void* d_out, int out_size, void* d_ws, size_t ws_size,
                              hipStream_t stream) {
    const float* inputs = (const float*)d_in[0];   // [B,4] fp32
    const float* rot = (const float*)d_in[1];      // [6,4,3] fp32
    float* out = (float*)d_out;                    // [B,4] fp32
    const int batch = in_sizes[0] / NQ;
    const int grid = (batch + BLOCK - 1) / BLOCK;
    vqc_kernel<<<grid, BLOCK, 0, stream>>>(inputs, rot, out, batch);
}